// Round 1
// baseline (9894.816 us; speedup 1.0000x reference)
//
#include <hip/hip_runtime.h>
#include <hip/hip_bf16.h>
#include <math.h>

#define BQ 2
#define SEQL 4096
#define DM 512
#define DIN 1024
#define DSTATE 128
#define NH 16
#define HD 64
#define DCONV 4
#define CONVDIM 1280
#define DINPROJ 2320
#define CHUNKL 128
#define NCHUNK 32
#define ROWS (BQ*SEQL)   // 8192

// ---------------- LayerNorm ----------------
__global__ __launch_bounds__(256) void ln_kernel(const float* __restrict__ in, const float* __restrict__ w,
                                                 const float* __restrict__ b, float* __restrict__ out) {
  int r = blockIdx.x;
  const float* x = in + (size_t)r * DM;
  float v[2];
  float s = 0.f, ss = 0.f;
  for (int i = 0; i < 2; i++) { v[i] = x[threadIdx.x + i*256]; s += v[i]; ss += v[i]*v[i]; }
  for (int o = 32; o > 0; o >>= 1) { s += __shfl_down(s, o); ss += __shfl_down(ss, o); }
  __shared__ float red[2][4];
  int lane = threadIdx.x & 63, wv = threadIdx.x >> 6;
  if (lane == 0) { red[0][wv] = s; red[1][wv] = ss; }
  __syncthreads();
  s  = red[0][0] + red[0][1] + red[0][2] + red[0][3];
  ss = red[1][0] + red[1][1] + red[1][2] + red[1][3];
  float mu = s * (1.f/DM);
  float var = ss * (1.f/DM) - mu*mu;
  float rstd = rsqrtf(var + 1e-5f);
  for (int i = 0; i < 2; i++) {
    int idx = threadIdx.x + i*256;
    out[(size_t)r*DM + idx] = (v[i]-mu)*rstd*w[idx] + b[idx];
  }
}

// ---------------- NT GEMM: C[M,N] = A[M,K] * B[N,K]^T (+C) ----------------
template<bool ADD>
__global__ __launch_bounds__(256) void gemm_nt(const float* __restrict__ A, const float* __restrict__ Bw,
                                               float* __restrict__ C, int N, int K) {
  __shared__ float As[16][65];
  __shared__ float Bs[16][65];
  int tid = threadIdx.x;
  int row0 = blockIdx.y * 64, col0 = blockIdx.x * 64;
  int tx = tid & 15, ty = tid >> 4;
  float acc[4][4];
  for (int i = 0; i < 4; i++) for (int j = 0; j < 4; j++) acc[i][j] = 0.f;
  int lr = tid >> 2, kq = (tid & 3) * 4;
  for (int k0 = 0; k0 < K; k0 += 16) {
    float4 av = *(const float4*)(A + (size_t)(row0 + lr)*K + k0 + kq);
    As[kq+0][lr] = av.x; As[kq+1][lr] = av.y; As[kq+2][lr] = av.z; As[kq+3][lr] = av.w;
    int n = col0 + lr;
    float4 bv = make_float4(0.f,0.f,0.f,0.f);
    if (n < N) bv = *(const float4*)(Bw + (size_t)n*K + k0 + kq);
    Bs[kq+0][lr] = bv.x; Bs[kq+1][lr] = bv.y; Bs[kq+2][lr] = bv.z; Bs[kq+3][lr] = bv.w;
    __syncthreads();
    #pragma unroll
    for (int k = 0; k < 16; k++) {
      float a0[4], b0[4];
      for (int i = 0; i < 4; i++) a0[i] = As[k][ty*4+i];
      for (int j = 0; j < 4; j++) b0[j] = Bs[k][tx*4+j];
      for (int i = 0; i < 4; i++)
        for (int j = 0; j < 4; j++)
          acc[i][j] += a0[i]*b0[j];
    }
    __syncthreads();
  }
  for (int i = 0; i < 4; i++) {
    int r = row0 + ty*4 + i;
    for (int j = 0; j < 4; j++) {
      int n = col0 + tx*4 + j;
      if (n < N) {
        size_t idx = (size_t)r*N + n;
        C[idx] = ADD ? (C[idx] + acc[i][j]) : acc[i][j];
      }
    }
  }
}

// ---------------- dt = softplus(raw + bias) ----------------
__global__ __launch_bounds__(256) void dt_kernel(const float* __restrict__ zx, const float* __restrict__ dtb,
                                                 float* __restrict__ dt) {
  int idx = blockIdx.x*256 + threadIdx.x;   // ROWS*NH
  int r = idx >> 4, j = idx & 15;
  float v = zx[(size_t)r*DINPROJ + 2304 + j] + dtb[j];
  dt[idx] = (v > 20.f) ? v : log1pf(__expf(v));
}

// ---------------- depthwise causal conv (width 4) + silu ----------------
__global__ __launch_bounds__(256) void conv_kernel(const float* __restrict__ zx, const float* __restrict__ cw,
                                                   const float* __restrict__ cb, float* __restrict__ xBC) {
  int idx = blockIdx.x*256 + threadIdx.x;   // ROWS*CONVDIM
  int r = idx / CONVDIM;
  int c = idx - r*CONVDIM;
  int b = r >> 12, l = r & 4095;
  float acc = cb[c];
  size_t rowb = ((size_t)b << 12) * DINPROJ;
  size_t colbase = 1024 + (size_t)c;
  if (l >= 3) {
    size_t p0 = rowb + (size_t)(l-3)*DINPROJ + colbase;
    acc += zx[p0]*cw[c*4+0] + zx[p0+DINPROJ]*cw[c*4+1]
         + zx[p0+2*DINPROJ]*cw[c*4+2] + zx[p0+3*DINPROJ]*cw[c*4+3];
  } else {
    for (int j = 0; j < 4; j++) {
      int ls = l - 3 + j;
      if (ls >= 0) acc += zx[rowb + (size_t)ls*DINPROJ + colbase]*cw[c*4+j];
    }
  }
  xBC[(size_t)r*CONVDIM + c] = acc / (1.f + __expf(-acc));
}

// ---------------- SSD intra-chunk: Y_diag + chunk states ----------------
__global__ __launch_bounds__(256) void ssd_intra(const float* __restrict__ xBC, const float* __restrict__ dt,
                                                 const float* __restrict__ Alog, float* __restrict__ Y,
                                                 float* __restrict__ states, float* __restrict__ acs_buf,
                                                 float* __restrict__ alast) {
  __shared__ float sX[CHUNKL][HD];            // 32 KB  X = xh*dt
  __shared__ float sB[CHUNKL][DSTATE];        // 64 KB
  __shared__ __hip_bfloat16 sC[CHUNKL][DSTATE+2]; // 32.5 KB (pad kills q-stride bank conflict)
  __shared__ float sa[CHUNKL];
  __shared__ float sdt[CHUNKL];
  int blk = blockIdx.x;       // (b*32 + c)*16 + h
  int h = blk & 15;
  int c = (blk >> 4) & 31;
  int b = blk >> 9;
  int t = threadIdx.x;
  size_t row0 = (size_t)(b*SEQL + c*CHUNKL);
  float Ah = -__expf(Alog[h]);
  if (t < CHUNKL) sdt[t] = dt[(row0 + t)*NH + h];
  __syncthreads();
  if (t == 0) {
    float cs = 0.f;
    for (int q = 0; q < CHUNKL; q++) { cs += sdt[q]*Ah; sa[q] = cs; }
  }
  for (int i = t; i < CHUNKL*HD; i += 256) {
    int q = i >> 6, pp = i & 63;
    sX[q][pp] = xBC[(row0+q)*CONVDIM + h*HD + pp] * sdt[q];
  }
  for (int i = t; i < CHUNKL*DSTATE; i += 256) {
    int q = i >> 7, n = i & 127;
    const float* rp = xBC + (row0+q)*CONVDIM + DIN;
    sB[q][n] = rp[n];
    sC[q][n] = __float2bfloat16(rp[DSTATE + n]);
  }
  __syncthreads();
  if (t < CHUNKL) acs_buf[(size_t)blk*CHUNKL + t] = sa[t];
  if (t == 0) alast[(b*NH + h)*NCHUNK + c] = sa[CHUNKL-1];
  // ---- Y_diag: thread pair per q, 32 p's each ----
  {
    int q = t >> 1, p0 = (t & 1)*32;
    float acc[32];
    for (int j = 0; j < 32; j++) acc[j] = 0.f;
    float aq = sa[q];
    for (int s = 0; s <= q; s++) {
      float dotv = 0.f;
      #pragma unroll 8
      for (int n = 0; n < DSTATE; n++) dotv += __bfloat162float(sC[q][n]) * sB[s][n];
      float wd = __expf(aq - sa[s]) * dotv;
      #pragma unroll
      for (int j = 0; j < 32; j++) acc[j] += wd * sX[s][p0+j];
    }
    float* yrow = Y + (row0+q)*DIN + h*HD + p0;
    for (int j = 0; j < 32; j++) yrow[j] = acc[j];
  }
  // ---- states[p][n] = sum_q exp(a_last - a_q) * X[q][p] * B[q][n] ----
  {
    int p = t & 63;             // distinct within wave
    int n0 = (t >> 6) * 32;     // wave-uniform n-group
    float acc[32];
    for (int j = 0; j < 32; j++) acc[j] = 0.f;
    float alastv = sa[CHUNKL-1];
    for (int q = 0; q < CHUNKL; q++) {
      float wx = __expf(alastv - sa[q]) * sX[q][p];
      #pragma unroll
      for (int j = 0; j < 32; j++) acc[j] += wx * sB[q][n0+j];
    }
    float* srow = states + (size_t)blk*(HD*DSTATE) + (size_t)p*DSTATE + n0;
    for (int j = 0; j < 32; j++) srow[j] = acc[j];
  }
}

// ---------------- inter-chunk scan (sequential over 32 chunks) ----------------
__global__ __launch_bounds__(256) void ssd_scan(float* __restrict__ states, const float* __restrict__ alast) {
  int b = blockIdx.x >> 4, h = blockIdx.x & 15;
  int t = threadIdx.x;
  float S[32];
  for (int j = 0; j < 32; j++) S[j] = 0.f;
  for (int c = 0; c < NCHUNK; c++) {
    float dec = __expf(alast[(b*NH + h)*NCHUNK + c]);
    float* base = states + ((size_t)((b*NCHUNK + c)*NH + h))*(HD*DSTATE);
    for (int j = 0; j < 32; j++) {
      int e = j*256 + t;
      float tmp = base[e];
      base[e] = S[j];          // becomes init_state for chunk c
      S[j] = dec*S[j] + tmp;
    }
  }
}

// ---------------- SSD off-diagonal: Y += exp(a_cs)*C@S_init^T + D*xh ----------------
__global__ __launch_bounds__(256) void ssd_off(const float* __restrict__ xBC, const float* __restrict__ states,
                                               const float* __restrict__ acs_buf, const float* __restrict__ Dvec,
                                               float* __restrict__ Y) {
  __shared__ float sS[HD][DSTATE+1];              // 33 KB
  __shared__ __hip_bfloat16 sC[CHUNKL][DSTATE+2]; // 32.5 KB
  __shared__ float sa[CHUNKL];
  int blk = blockIdx.x;
  int h = blk & 15; int c = (blk >> 4) & 31; int b = blk >> 9;
  int t = threadIdx.x;
  size_t row0 = (size_t)(b*SEQL + c*CHUNKL);
  const float* sbase = states + (size_t)blk*(HD*DSTATE);
  for (int i = t; i < HD*DSTATE; i += 256) sS[i >> 7][i & 127] = sbase[i];
  for (int i = t; i < CHUNKL*DSTATE; i += 256) {
    int q = i >> 7, n = i & 127;
    sC[q][n] = __float2bfloat16(xBC[(row0+q)*CONVDIM + DIN + DSTATE + n]);
  }
  if (t < CHUNKL) sa[t] = acs_buf[(size_t)blk*CHUNKL + t];
  __syncthreads();
  int q = t >> 1, p0 = (t & 1)*32;
  float acc[32];
  for (int j = 0; j < 32; j++) acc[j] = 0.f;
  for (int n = 0; n < DSTATE; n++) {
    float cv = __bfloat162float(sC[q][n]);
    #pragma unroll
    for (int j = 0; j < 32; j++) acc[j] += cv * sS[p0+j][n];
  }
  float ea = __expf(sa[q]);
  float Dh = Dvec[h];
  const float* xrow = xBC + (row0+q)*CONVDIM + h*HD + p0;
  float* yrow = Y + (row0+q)*DIN + h*HD + p0;
  for (int j = 0; j < 32; j++) yrow[j] += ea*acc[j] + Dh*xrow[j];
}

// ---------------- gate (silu(z)) + RMSNorm ----------------
__global__ __launch_bounds__(256) void gate_rms(const float* __restrict__ zx, const float* __restrict__ Y,
                                                const float* __restrict__ rw, float* __restrict__ out) {
  int r = blockIdx.x;
  int t = threadIdx.x;
  float yz[4];
  float ss = 0.f;
  for (int i = 0; i < 4; i++) {
    int idx = t + i*256;
    float z = zx[(size_t)r*DINPROJ + idx];
    float y = Y[(size_t)r*DIN + idx];
    float v = y * z / (1.f + __expf(-z));
    yz[i] = v; ss += v*v;
  }
  for (int o = 32; o > 0; o >>= 1) ss += __shfl_down(ss, o);
  __shared__ float red[4];
  int lane = t & 63, wv = t >> 6;
  if (lane == 0) red[wv] = ss;
  __syncthreads();
  ss = red[0]+red[1]+red[2]+red[3];
  float rs = rsqrtf(ss*(1.f/DIN) + 1e-5f);
  for (int i = 0; i < 4; i++) {
    int idx = t + i*256;
    out[(size_t)r*DIN + idx] = yz[i]*rs*rw[idx];
  }
}

extern "C" void kernel_launch(void* const* d_in, const int* in_sizes, int n_in,
                              void* d_out, int out_size, void* d_ws, size_t ws_size,
                              hipStream_t stream) {
  (void)in_sizes; (void)n_in; (void)out_size; (void)ws_size;
  const float* x    = (const float*)d_in[0];
  const float* Wi   = (const float*)d_in[1];
  const float* cw   = (const float*)d_in[2];
  const float* cb   = (const float*)d_in[3];
  const float* dtb  = (const float*)d_in[4];
  const float* Alog = (const float*)d_in[5];
  const float* Dv   = (const float*)d_in[6];
  const float* rw   = (const float*)d_in[7];
  const float* Wo   = (const float*)d_in[8];
  const float* lnw  = (const float*)d_in[9];
  const float* lnb  = (const float*)d_in[10];
  const float* flnw = (const float*)d_in[11];
  const float* flnb = (const float*)d_in[12];
  float* out = (float*)d_out;

  float* p = (float*)d_ws;
  float* buf_h   = p; p += (size_t)ROWS*DM;        // 4.19M
  float* buf_hn  = p; p += (size_t)ROWS*DM;        // 4.19M (also holds gated/rms y)
  float* buf_zx  = p; p += (size_t)ROWS*DINPROJ;   // 19.0M
  float* buf_xBC = p; p += (size_t)ROWS*CONVDIM;   // 10.5M
  float* buf_dt  = p; p += (size_t)ROWS*NH;        // 0.13M
  float* buf_Y   = p; p += (size_t)ROWS*DIN;       // 8.39M
  float* buf_st  = p; p += (size_t)BQ*NCHUNK*NH*HD*DSTATE; // 8.39M
  float* buf_acs = p; p += (size_t)BQ*NCHUNK*NH*CHUNKL;    // 0.13M
  float* buf_al  = p; p += (size_t)BQ*NH*NCHUNK;           // 1K

  hipMemcpyAsync(buf_h, x, (size_t)ROWS*DM*sizeof(float), hipMemcpyDeviceToDevice, stream);

  for (int i = 0; i < 6; i++) {
    ln_kernel<<<ROWS, 256, 0, stream>>>(buf_h, lnw + i*DM, lnb + i*DM, buf_hn);
    gemm_nt<false><<<dim3((DINPROJ+63)/64, ROWS/64), 256, 0, stream>>>(
        buf_hn, Wi + (size_t)i*DINPROJ*DM, buf_zx, DINPROJ, DM);
    dt_kernel<<<ROWS*NH/256, 256, 0, stream>>>(buf_zx, dtb + i*NH, buf_dt);
    conv_kernel<<<ROWS*CONVDIM/256, 256, 0, stream>>>(
        buf_zx, cw + (size_t)i*CONVDIM*DCONV, cb + i*CONVDIM, buf_xBC);
    ssd_intra<<<BQ*NCHUNK*NH, 256, 0, stream>>>(
        buf_xBC, buf_dt, Alog + i*NH, buf_Y, buf_st, buf_acs, buf_al);
    ssd_scan<<<BQ*NH, 256, 0, stream>>>(buf_st, buf_al);
    ssd_off<<<BQ*NCHUNK*NH, 256, 0, stream>>>(buf_xBC, buf_st, buf_acs, Dv + i*NH, buf_Y);
    gate_rms<<<ROWS, 256, 0, stream>>>(buf_zx, buf_Y, rw + i*DIN, buf_hn);
    gemm_nt<true><<<dim3(DM/64, ROWS/64), 256, 0, stream>>>(
        buf_hn, Wo + (size_t)i*DM*DIN, buf_h, DM, DIN);
  }
  ln_kernel<<<ROWS, 256, 0, stream>>>(buf_h, flnw, flnb, out);
}

// Round 2
// 1901.828 us; speedup vs baseline: 5.2028x; 5.2028x over previous
//
#include <hip/hip_runtime.h>
#include <hip/hip_bf16.h>
#include <math.h>

#define BQ 2
#define SEQL 4096
#define DM 512
#define DIN 1024
#define DSTATE 128
#define NH 16
#define HD 64
#define DCONV 4
#define CONVDIM 1280
#define DINPROJ 2320
#define CHUNKL 128
#define NCHUNK 32
#define ROWS (BQ*SEQL)   // 8192
#define NPAD 2432        // 19*128, padded in_proj N

typedef __attribute__((ext_vector_type(8))) short short8;
typedef __attribute__((ext_vector_type(4))) float f32x4;

// ---------------- LayerNorm (+ optional bf16 copy of output) ----------------
__global__ __launch_bounds__(256) void ln_kernel(const float* __restrict__ in, const float* __restrict__ w,
                                                 const float* __restrict__ b, float* __restrict__ out,
                                                 __hip_bfloat16* __restrict__ outb) {
  int r = blockIdx.x;
  const float* x = in + (size_t)r * DM;
  float v[2];
  float s = 0.f, ss = 0.f;
  for (int i = 0; i < 2; i++) { v[i] = x[threadIdx.x + i*256]; s += v[i]; ss += v[i]*v[i]; }
  for (int o = 32; o > 0; o >>= 1) { s += __shfl_down(s, o); ss += __shfl_down(ss, o); }
  __shared__ float red[2][4];
  int lane = threadIdx.x & 63, wv = threadIdx.x >> 6;
  if (lane == 0) { red[0][wv] = s; red[1][wv] = ss; }
  __syncthreads();
  s  = red[0][0] + red[0][1] + red[0][2] + red[0][3];
  ss = red[1][0] + red[1][1] + red[1][2] + red[1][3];
  float mu = s * (1.f/DM);
  float var = ss * (1.f/DM) - mu*mu;
  float rstd = rsqrtf(var + 1e-5f);
  for (int i = 0; i < 2; i++) {
    int idx = threadIdx.x + i*256;
    float val = (v[i]-mu)*rstd*w[idx] + b[idx];
    out[(size_t)r*DM + idx] = val;
    if (outb) outb[(size_t)r*DM + idx] = __float2bfloat16(val);
  }
}

// ---------------- weight fp32 -> bf16 conversions (once per call) ----------------
__global__ __launch_bounds__(256) void cvt_wi(const float* __restrict__ Wi, __hip_bfloat16* __restrict__ out) {
  int idx = blockIdx.x*256 + threadIdx.x;   // 6*NPAD*512
  int l = idx / (NPAD*DM);
  int r = idx - l*(NPAD*DM);
  int n = r >> 9, k = r & 511;
  float v = (n < DINPROJ) ? Wi[(size_t)l*DINPROJ*DM + (size_t)n*DM + k] : 0.f;
  out[idx] = __float2bfloat16(v);
}
__global__ __launch_bounds__(256) void cvt_wo(const float* __restrict__ Wo, __hip_bfloat16* __restrict__ out) {
  size_t idx = (size_t)blockIdx.x*256 + threadIdx.x;  // 6*512*1024
  out[idx] = __float2bfloat16(Wo[idx]);
}

// ---------------- bf16 MFMA NT GEMM: C[M,N] = A[M,K] * B[N,K]^T (+C) ----------------
// A row-major bf16 (M x K), Bw row-major bf16 (Npad x K). 128x128 tile, BK=64.
// global_load_lds width-16 staging with XOR-chunk swizzle (conflict-free ds_read_b128).
template<bool ADD>
__global__ __launch_bounds__(256) void gemm_bf16(const __hip_bfloat16* __restrict__ A,
                                                 const __hip_bfloat16* __restrict__ Bw,
                                                 float* __restrict__ C, int N, int K) {
  __shared__ __hip_bfloat16 sA[128*64];
  __shared__ __hip_bfloat16 sB[128*64];
  int tid = threadIdx.x;
  int w = tid >> 6, lane = tid & 63;
  int quad = lane >> 4, l16 = lane & 15;
  int row0 = blockIdx.y * 128, col0 = blockIdx.x * 128;
  int srow = lane >> 3;       // 0..7 within 8-row group
  int schunk = lane & 7;      // 16B chunk within 128B row
  f32x4 acc[4][4];
  #pragma unroll
  for (int i = 0; i < 4; i++)
    #pragma unroll
    for (int j = 0; j < 4; j++) acc[i][j] = (f32x4){0.f,0.f,0.f,0.f};
  int wrow = (w >> 1) * 64, wcol = (w & 1) * 64;
  for (int k0 = 0; k0 < K; k0 += 64) {
    #pragma unroll
    for (int j = 0; j < 4; j++) {
      int r = w*32 + j*8 + srow;                 // 0..127
      int gc = (schunk ^ (r & 7)) * 8;           // swizzled source col (elements)
      const __hip_bfloat16* ga = A + (size_t)(row0 + r)*K + k0 + gc;
      __builtin_amdgcn_global_load_lds((const __attribute__((address_space(1))) void*)ga,
          (__attribute__((address_space(3))) void*)(sA + (w*32 + j*8)*64), 16, 0, 0);
      const __hip_bfloat16* gb = Bw + (size_t)(col0 + r)*K + k0 + gc;
      __builtin_amdgcn_global_load_lds((const __attribute__((address_space(1))) void*)gb,
          (__attribute__((address_space(3))) void*)(sB + (w*32 + j*8)*64), 16, 0, 0);
    }
    __syncthreads();
    #pragma unroll
    for (int ks = 0; ks < 64; ks += 32) {
      short8 af[4], bfv[4];
      #pragma unroll
      for (int mt = 0; mt < 4; mt++) {
        int r = wrow + mt*16 + l16;
        int cch = (ks/8 + quad) ^ (r & 7);
        af[mt] = *(const short8*)(sA + r*64 + cch*8);
      }
      #pragma unroll
      for (int nt = 0; nt < 4; nt++) {
        int r = wcol + nt*16 + l16;
        int cch = (ks/8 + quad) ^ (r & 7);
        bfv[nt] = *(const short8*)(sB + r*64 + cch*8);
      }
      #pragma unroll
      for (int mt = 0; mt < 4; mt++)
        #pragma unroll
        for (int nt = 0; nt < 4; nt++)
          acc[mt][nt] = __builtin_amdgcn_mfma_f32_16x16x32_bf16(af[mt], bfv[nt], acc[mt][nt], 0, 0, 0);
    }
    __syncthreads();
  }
  #pragma unroll
  for (int mt = 0; mt < 4; mt++) {
    int r = row0 + wrow + mt*16 + quad*4;
    #pragma unroll
    for (int nt = 0; nt < 4; nt++) {
      int cidx = col0 + wcol + nt*16 + l16;
      if (cidx < N) {
        float* cp = C + (size_t)r*N + cidx;
        #pragma unroll
        for (int rg = 0; rg < 4; rg++) {
          float v = acc[mt][nt][rg];
          size_t off = (size_t)rg*N;
          if (ADD) cp[off] += v; else cp[off] = v;
        }
      }
    }
  }
}

// ---------------- exact fp32 dt: dt = softplus(hn @ Wi_dt^T + dtb) ----------------
__global__ __launch_bounds__(256) void dt_exact(const float* __restrict__ hn, const float* __restrict__ Wi,
                                                const float* __restrict__ dtb, float* __restrict__ dtout) {
  int r = blockIdx.x;
  __shared__ float sh[512];
  __shared__ float red[16][17];
  int t = threadIdx.x;
  sh[t] = hn[(size_t)r*DM + t];
  sh[t+256] = hn[(size_t)r*DM + t + 256];
  __syncthreads();
  int j = t >> 4, seg = t & 15;
  const float* wrow = Wi + (size_t)(2304 + j)*DM + seg*32;
  float p = 0.f;
  #pragma unroll
  for (int k = 0; k < 32; k++) p += sh[seg*32 + k] * wrow[k];
  red[j][seg] = p;
  __syncthreads();
  if (t < 16) {
    float v = 0.f;
    for (int s = 0; s < 16; s++) v += red[t][s];
    v += dtb[t];
    dtout[r*NH + t] = (v > 20.f) ? v : log1pf(__expf(v));
  }
}

// ---------------- depthwise causal conv (width 4) + silu ----------------
__global__ __launch_bounds__(256) void conv_kernel(const float* __restrict__ zx, const float* __restrict__ cw,
                                                   const float* __restrict__ cb, float* __restrict__ xBC) {
  int idx = blockIdx.x*256 + threadIdx.x;
  int r = idx / CONVDIM;
  int c = idx - r*CONVDIM;
  int b = r >> 12, l = r & 4095;
  float acc = cb[c];
  size_t rowb = ((size_t)b << 12) * DINPROJ;
  size_t colbase = 1024 + (size_t)c;
  if (l >= 3) {
    size_t p0 = rowb + (size_t)(l-3)*DINPROJ + colbase;
    acc += zx[p0]*cw[c*4+0] + zx[p0+DINPROJ]*cw[c*4+1]
         + zx[p0+2*DINPROJ]*cw[c*4+2] + zx[p0+3*DINPROJ]*cw[c*4+3];
  } else {
    for (int j = 0; j < 4; j++) {
      int ls = l - 3 + j;
      if (ls >= 0) acc += zx[rowb + (size_t)ls*DINPROJ + colbase]*cw[c*4+j];
    }
  }
  xBC[(size_t)r*CONVDIM + c] = acc / (1.f + __expf(-acc));
}

// ---------------- SSD intra-chunk, MFMA version ----------------
// Per block (b,c,h): G = C·B^T (K=128) -> mask/decay -> M (bf16, in sC)
// Y_diag = M·X ; states = X^T·Bw  (w[q]=exp(a_last-a_q) folded into B)
__global__ __launch_bounds__(256) void ssd_intra_mfma(const float* __restrict__ xBC, const float* __restrict__ dt,
                                                      const float* __restrict__ Alog, float* __restrict__ Y,
                                                      float* __restrict__ states, float* __restrict__ acs_buf,
                                                      float* __restrict__ alast) {
  __shared__ __hip_bfloat16 sC[128][136];    // C rows; reused for M
  __shared__ __hip_bfloat16 sB[128][136];    // B rows [s][n]
  __shared__ __hip_bfloat16 sBwt[128][136];  // Bw^T [n][q]
  __shared__ __hip_bfloat16 sXt[64][136];    // X^T [p][q]  (X = xh*dt)
  __shared__ float sa[128], sdt_s[128], sw[128];
  int blk = blockIdx.x;                      // (b*32 + c)*16 + h
  int h = blk & 15, c = (blk >> 4) & 31, b = blk >> 9;
  int t = threadIdx.x;
  int w = t >> 6, lane = t & 63, quad = lane >> 4, l16 = lane & 15;
  size_t row0 = (size_t)(b*SEQL + c*CHUNKL);
  float Ah = -__expf(Alog[h]);
  if (t < 128) sdt_s[t] = dt[(row0 + t)*NH + h];
  __syncthreads();
  if (t == 0) { float cs = 0.f; for (int q = 0; q < 128; q++) { cs += sdt_s[q]*Ah; sa[q] = cs; } }
  for (int i = t; i < 128*64; i += 256) {
    int q = i >> 6, p = i & 63;
    sXt[p][q] = __float2bfloat16(xBC[(row0+q)*CONVDIM + h*HD + p] * sdt_s[q]);
  }
  for (int i = t; i < 128*128; i += 256) {
    int q = i >> 7, n = i & 127;
    const float* rp = xBC + (row0+q)*CONVDIM + DIN;
    float bv = rp[n];
    sB[q][n] = __float2bfloat16(bv);
    sBwt[n][q] = __float2bfloat16(bv);
    sC[q][n] = __float2bfloat16(rp[DSTATE + n]);
  }
  __syncthreads();
  if (t < 128) { sw[t] = __expf(sa[127] - sa[t]); acs_buf[(size_t)blk*128 + t] = sa[t]; }
  if (t == 0) alast[(b*NH + h)*NCHUNK + c] = sa[127];
  __syncthreads();
  for (int i = t; i < 128*128; i += 256) {
    int n = i >> 7, q = i & 127;
    sBwt[n][q] = __float2bfloat16(__bfloat162float(sBwt[n][q]) * sw[q]);
  }
  __syncthreads();
  // step 1: G = C·B^T  (wave: m-tiles {2w,2w+1} x 8 n-tiles)
  f32x4 g[2][8];
  #pragma unroll
  for (int mt = 0; mt < 2; mt++)
    #pragma unroll
    for (int nt = 0; nt < 8; nt++) g[mt][nt] = (f32x4){0.f,0.f,0.f,0.f};
  #pragma unroll
  for (int ks = 0; ks < 128; ks += 32) {
    short8 af[2], bfv[8];
    #pragma unroll
    for (int mt = 0; mt < 2; mt++) af[mt] = *(const short8*)&sC[(w*2+mt)*16 + l16][ks + quad*8];
    #pragma unroll
    for (int nt = 0; nt < 8; nt++) bfv[nt] = *(const short8*)&sB[nt*16 + l16][ks + quad*8];
    #pragma unroll
    for (int mt = 0; mt < 2; mt++)
      #pragma unroll
      for (int nt = 0; nt < 8; nt++)
        g[mt][nt] = __builtin_amdgcn_mfma_f32_16x16x32_bf16(af[mt], bfv[nt], g[mt][nt], 0, 0, 0);
  }
  __syncthreads();   // all reads of sC done
  // write M = L ⊙ G into sC (bf16)
  #pragma unroll
  for (int mt = 0; mt < 2; mt++) {
    int qb = (w*2+mt)*16 + quad*4;
    #pragma unroll
    for (int nt = 0; nt < 8; nt++) {
      int s = nt*16 + l16;
      #pragma unroll
      for (int rg = 0; rg < 4; rg++) {
        int qq = qb + rg;
        float m = (s <= qq) ? g[mt][nt][rg] * __expf(sa[qq] - sa[s]) : 0.f;
        sC[qq][s] = __float2bfloat16(m);
      }
    }
  }
  __syncthreads();
  // step 3: Y_diag = M·X  (m-tiles {2w,2w+1} x 4 n-tiles of p)
  f32x4 y4[2][4];
  #pragma unroll
  for (int mt = 0; mt < 2; mt++)
    #pragma unroll
    for (int nt = 0; nt < 4; nt++) y4[mt][nt] = (f32x4){0.f,0.f,0.f,0.f};
  #pragma unroll
  for (int ks = 0; ks < 128; ks += 32) {
    short8 af[2], bfv[4];
    #pragma unroll
    for (int mt = 0; mt < 2; mt++) af[mt] = *(const short8*)&sC[(w*2+mt)*16 + l16][ks + quad*8];
    #pragma unroll
    for (int nt = 0; nt < 4; nt++) bfv[nt] = *(const short8*)&sXt[nt*16 + l16][ks + quad*8];
    #pragma unroll
    for (int mt = 0; mt < 2; mt++)
      #pragma unroll
      for (int nt = 0; nt < 4; nt++)
        y4[mt][nt] = __builtin_amdgcn_mfma_f32_16x16x32_bf16(af[mt], bfv[nt], y4[mt][nt], 0, 0, 0);
  }
  // step 4: states = X^T·Bw  (wave w: m-tile w of p, 8 n-tiles)
  f32x4 st4[8];
  #pragma unroll
  for (int nt = 0; nt < 8; nt++) st4[nt] = (f32x4){0.f,0.f,0.f,0.f};
  #pragma unroll
  for (int ks = 0; ks < 128; ks += 32) {
    short8 af = *(const short8*)&sXt[w*16 + l16][ks + quad*8];
    short8 bfv[8];
    #pragma unroll
    for (int nt = 0; nt < 8; nt++) bfv[nt] = *(const short8*)&sBwt[nt*16 + l16][ks + quad*8];
    #pragma unroll
    for (int nt = 0; nt < 8; nt++)
      st4[nt] = __builtin_amdgcn_mfma_f32_16x16x32_bf16(af, bfv[nt], st4[nt], 0, 0, 0);
  }
  #pragma unroll
  for (int mt = 0; mt < 2; mt++) {
    int qb = (w*2+mt)*16 + quad*4;
    #pragma unroll
    for (int nt = 0; nt < 4; nt++) {
      int p = nt*16 + l16;
      #pragma unroll
      for (int rg = 0; rg < 4; rg++)
        Y[(row0 + qb + rg)*DIN + h*HD + p] = y4[mt][nt][rg];
    }
  }
  {
    int pb = w*16 + quad*4;
    float* sp = states + (size_t)blk*(HD*DSTATE);
    #pragma unroll
    for (int nt = 0; nt < 8; nt++) {
      int n = nt*16 + l16;
      #pragma unroll
      for (int rg = 0; rg < 4; rg++)
        sp[(size_t)(pb + rg)*DSTATE + n] = st4[nt][rg];
    }
  }
}

// ---------------- inter-chunk scan: one thread per (b,h,p,n) ----------------
__global__ __launch_bounds__(256) void ssd_scan2(float* __restrict__ states, const float* __restrict__ alast) {
  int idx = blockIdx.x*256 + threadIdx.x;     // 2*16*8192
  int b = idx >> 17;
  int h = (idx >> 13) & 15;
  int pn = idx & 8191;
  const float* al = alast + (b*NH + h)*NCHUNK;
  float S = 0.f;
  for (int c = 0; c < NCHUNK; c++) {
    size_t base = ((size_t)((b*NCHUNK + c)*NH + h))*8192 + pn;
    float dec = __expf(al[c]);
    float tmp = states[base];
    states[base] = S;
    S = dec*S + tmp;
  }
}

// ---------------- SSD off-diagonal, MFMA: Y += exp(a_cs)·C·S^T + D·xh ----------------
__global__ __launch_bounds__(256) void ssd_off_mfma(const float* __restrict__ xBC, const float* __restrict__ states,
                                                    const float* __restrict__ acs_buf, const float* __restrict__ Dvec,
                                                    float* __restrict__ Y) {
  __shared__ __hip_bfloat16 sC[128][136];   // C rows [q][n]
  __shared__ __hip_bfloat16 sS[64][136];    // S rows [p][n]
  __shared__ float sa[128];
  int blk = blockIdx.x;
  int h = blk & 15, c = (blk >> 4) & 31, b = blk >> 9;
  int t = threadIdx.x;
  int w = t >> 6, lane = t & 63, quad = lane >> 4, l16 = lane & 15;
  size_t row0 = (size_t)(b*SEQL + c*CHUNKL);
  const float* sbase = states + (size_t)blk*(HD*DSTATE);
  for (int i = t; i < 128*128; i += 256) {
    int q = i >> 7, n = i & 127;
    sC[q][n] = __float2bfloat16(xBC[(row0+q)*CONVDIM + DIN + DSTATE + n]);
  }
  for (int i = t; i < 64*128; i += 256) {
    int p = i >> 7, n = i & 127;
    sS[p][n] = __float2bfloat16(sbase[(size_t)p*DSTATE + n]);
  }
  if (t < 128) sa[t] = acs_buf[(size_t)blk*128 + t];
  __syncthreads();
  f32x4 acc[2][4];
  #pragma unroll
  for (int mt = 0; mt < 2; mt++)
    #pragma unroll
    for (int nt = 0; nt < 4; nt++) acc[mt][nt] = (f32x4){0.f,0.f,0.f,0.f};
  #pragma unroll
  for (int ks = 0; ks < 128; ks += 32) {
    short8 af[2], bfv[4];
    #pragma unroll
    for (int mt = 0; mt < 2; mt++) af[mt] = *(const short8*)&sC[(w*2+mt)*16 + l16][ks + quad*8];
    #pragma unroll
    for (int nt = 0; nt < 4; nt++) bfv[nt] = *(const short8*)&sS[nt*16 + l16][ks + quad*8];
    #pragma unroll
    for (int mt = 0; mt < 2; mt++)
      #pragma unroll
      for (int nt = 0; nt < 4; nt++)
        acc[mt][nt] = __builtin_amdgcn_mfma_f32_16x16x32_bf16(af[mt], bfv[nt], acc[mt][nt], 0, 0, 0);
  }
  float Dh = Dvec[h];
  #pragma unroll
  for (int mt = 0; mt < 2; mt++) {
    int qb = (w*2+mt)*16 + quad*4;
    #pragma unroll
    for (int rg = 0; rg < 4; rg++) {
      int q = qb + rg;
      float ea = __expf(sa[q]);
      #pragma unroll
      for (int nt = 0; nt < 4; nt++) {
        int p = nt*16 + l16;
        size_t yi = (row0 + q)*DIN + h*HD + p;
        Y[yi] += ea*acc[mt][nt][rg] + Dh*xBC[(row0+q)*CONVDIM + h*HD + p];
      }
    }
  }
}

// ---------------- gate (silu(z)) + RMSNorm -> bf16 ----------------
__global__ __launch_bounds__(256) void gate_rms(const float* __restrict__ zx, const float* __restrict__ Y,
                                                const float* __restrict__ rw, __hip_bfloat16* __restrict__ out) {
  int r = blockIdx.x;
  int t = threadIdx.x;
  float yz[4];
  float ss = 0.f;
  for (int i = 0; i < 4; i++) {
    int idx = t + i*256;
    float z = zx[(size_t)r*DINPROJ + idx];
    float y = Y[(size_t)r*DIN + idx];
    float v = y * z / (1.f + __expf(-z));
    yz[i] = v; ss += v*v;
  }
  for (int o = 32; o > 0; o >>= 1) ss += __shfl_down(ss, o);
  __shared__ float red[4];
  int lane = t & 63, wv = t >> 6;
  if (lane == 0) red[wv] = ss;
  __syncthreads();
  ss = red[0]+red[1]+red[2]+red[3];
  float rs = rsqrtf(ss*(1.f/DIN) + 1e-5f);
  for (int i = 0; i < 4; i++) {
    int idx = t + i*256;
    out[(size_t)r*DIN + idx] = __float2bfloat16(yz[i]*rs*rw[idx]);
  }
}

extern "C" void kernel_launch(void* const* d_in, const int* in_sizes, int n_in,
                              void* d_out, int out_size, void* d_ws, size_t ws_size,
                              hipStream_t stream) {
  (void)in_sizes; (void)n_in; (void)out_size; (void)ws_size;
  const float* x    = (const float*)d_in[0];
  const float* Wi   = (const float*)d_in[1];
  const float* cw   = (const float*)d_in[2];
  const float* cb   = (const float*)d_in[3];
  const float* dtb  = (const float*)d_in[4];
  const float* Alog = (const float*)d_in[5];
  const float* Dv   = (const float*)d_in[6];
  const float* rw   = (const float*)d_in[7];
  const float* Wo   = (const float*)d_in[8];
  const float* lnw  = (const float*)d_in[9];
  const float* lnb  = (const float*)d_in[10];
  const float* flnw = (const float*)d_in[11];
  const float* flnb = (const float*)d_in[12];
  float* out = (float*)d_out;

  float* p = (float*)d_ws;
  float* buf_h   = p; p += (size_t)ROWS*DM;
  float* buf_hn  = p; p += (size_t)ROWS*DM;
  float* buf_zx  = p; p += (size_t)ROWS*DINPROJ;
  float* buf_xBC = p; p += (size_t)ROWS*CONVDIM;
  float* buf_dt  = p; p += (size_t)ROWS*NH;
  float* buf_Y   = p; p += (size_t)ROWS*DIN;
  float* buf_st  = p; p += (size_t)BQ*NCHUNK*NH*HD*DSTATE;
  float* buf_acs = p; p += (size_t)BQ*NCHUNK*NH*CHUNKL;
  float* buf_al  = p; p += (size_t)BQ*NH*NCHUNK;
  __hip_bfloat16* bp = (__hip_bfloat16*)p;
  __hip_bfloat16* wi_b = bp; bp += (size_t)6*NPAD*DM;
  __hip_bfloat16* wo_b = bp; bp += (size_t)6*DM*DIN;
  __hip_bfloat16* hn_b = bp; bp += (size_t)ROWS*DM;
  __hip_bfloat16* y_b  = bp; bp += (size_t)ROWS*DIN;

  hipMemcpyAsync(buf_h, x, (size_t)ROWS*DM*sizeof(float), hipMemcpyDeviceToDevice, stream);
  cvt_wi<<<6*NPAD*DM/256, 256, 0, stream>>>(Wi, wi_b);
  cvt_wo<<<6*DM*DIN/256, 256, 0, stream>>>(Wo, wo_b);

  for (int i = 0; i < 6; i++) {
    ln_kernel<<<ROWS, 256, 0, stream>>>(buf_h, lnw + i*DM, lnb + i*DM, buf_hn, hn_b);
    dt_exact<<<ROWS, 256, 0, stream>>>(buf_hn, Wi + (size_t)i*DINPROJ*DM, dtb + i*NH, buf_dt);
    gemm_bf16<false><<<dim3(NPAD/128, ROWS/128), 256, 0, stream>>>(
        hn_b, wi_b + (size_t)i*NPAD*DM, buf_zx, DINPROJ, DM);
    conv_kernel<<<ROWS*CONVDIM/256, 256, 0, stream>>>(
        buf_zx, cw + (size_t)i*CONVDIM*DCONV, cb + i*CONVDIM, buf_xBC);
    ssd_intra_mfma<<<BQ*NCHUNK*NH, 256, 0, stream>>>(
        buf_xBC, buf_dt, Alog + i*NH, buf_Y, buf_st, buf_acs, buf_al);
    ssd_scan2<<<BQ*NH*HD*DSTATE/256, 256, 0, stream>>>(buf_st, buf_al);
    ssd_off_mfma<<<BQ*NCHUNK*NH, 256, 0, stream>>>(buf_xBC, buf_st, buf_acs, Dv + i*NH, buf_Y);
    gate_rms<<<ROWS, 256, 0, stream>>>(buf_zx, buf_Y, rw + i*DIN, y_b);
    gemm_bf16<true><<<dim3(DM/128, ROWS/128), 256, 0, stream>>>(
        y_b, wo_b + (size_t)i*DM*DIN, buf_h, DM, DIN);
  }
  ln_kernel<<<ROWS, 256, 0, stream>>>(buf_h, flnw, flnb, out, nullptr);
}

// Round 3
// 1686.922 us; speedup vs baseline: 5.8656x; 1.1274x over previous
//
#include <hip/hip_runtime.h>
#include <hip/hip_bf16.h>
#include <math.h>

#define BQ 2
#define SEQL 4096
#define DM 512
#define DIN 1024
#define DSTATE 128
#define NH 16
#define HD 64
#define DCONV 4
#define CONVDIM 1280
#define DINPROJ 2320
#define CHUNKL 128
#define NCHUNK 32
#define ROWS (BQ*SEQL)   // 8192
#define NPAD 2432        // 19*128, padded in_proj N

typedef __attribute__((ext_vector_type(8))) short short8;
typedef __attribute__((ext_vector_type(4))) short short4v;
typedef __attribute__((ext_vector_type(4))) float f32x4;

__device__ __forceinline__ short bfs(float f) {
  __hip_bfloat16 h = __float2bfloat16(f);
  short s; __builtin_memcpy(&s, &h, 2); return s;
}

// ---------------- LayerNorm (+ optional bf16 copy of output) ----------------
__global__ __launch_bounds__(256) void ln_kernel(const float* __restrict__ in, const float* __restrict__ w,
                                                 const float* __restrict__ b, float* __restrict__ out,
                                                 __hip_bfloat16* __restrict__ outb) {
  int r = blockIdx.x;
  const float* x = in + (size_t)r * DM;
  float v[2];
  float s = 0.f, ss = 0.f;
  for (int i = 0; i < 2; i++) { v[i] = x[threadIdx.x + i*256]; s += v[i]; ss += v[i]*v[i]; }
  for (int o = 32; o > 0; o >>= 1) { s += __shfl_down(s, o); ss += __shfl_down(ss, o); }
  __shared__ float red[2][4];
  int lane = threadIdx.x & 63, wv = threadIdx.x >> 6;
  if (lane == 0) { red[0][wv] = s; red[1][wv] = ss; }
  __syncthreads();
  s  = red[0][0] + red[0][1] + red[0][2] + red[0][3];
  ss = red[1][0] + red[1][1] + red[1][2] + red[1][3];
  float mu = s * (1.f/DM);
  float var = ss * (1.f/DM) - mu*mu;
  float rstd = rsqrtf(var + 1e-5f);
  for (int i = 0; i < 2; i++) {
    int idx = threadIdx.x + i*256;
    float val = (v[i]-mu)*rstd*w[idx] + b[idx];
    out[(size_t)r*DM + idx] = val;
    if (outb) outb[(size_t)r*DM + idx] = __float2bfloat16(val);
  }
}

// ---------------- weight fp32 -> bf16 conversions (once per call) ----------------
__global__ __launch_bounds__(256) void cvt_wi(const float* __restrict__ Wi, __hip_bfloat16* __restrict__ out) {
  int idx = blockIdx.x*256 + threadIdx.x;   // 6*NPAD*512
  int l = idx / (NPAD*DM);
  int r = idx - l*(NPAD*DM);
  int n = r >> 9, k = r & 511;
  float v = (n < DINPROJ) ? Wi[(size_t)l*DINPROJ*DM + (size_t)n*DM + k] : 0.f;
  out[idx] = __float2bfloat16(v);
}
__global__ __launch_bounds__(256) void cvt_wo(const float* __restrict__ Wo, __hip_bfloat16* __restrict__ out) {
  size_t idx = (size_t)blockIdx.x*256 + threadIdx.x;  // 6*512*1024
  out[idx] = __float2bfloat16(Wo[idx]);
}

// ---------------- bf16 MFMA NT GEMM: C[M,N] = A[M,K] * B[N,K]^T (+C) ----------------
template<bool ADD>
__global__ __launch_bounds__(256) void gemm_bf16(const __hip_bfloat16* __restrict__ A,
                                                 const __hip_bfloat16* __restrict__ Bw,
                                                 float* __restrict__ C, int N, int K) {
  __shared__ __hip_bfloat16 sA[128*64];
  __shared__ __hip_bfloat16 sB[128*64];
  int tid = threadIdx.x;
  int w = tid >> 6, lane = tid & 63;
  int quad = lane >> 4, l16 = lane & 15;
  int row0 = blockIdx.y * 128, col0 = blockIdx.x * 128;
  int srow = lane >> 3;
  int schunk = lane & 7;
  f32x4 acc[4][4];
  #pragma unroll
  for (int i = 0; i < 4; i++)
    #pragma unroll
    for (int j = 0; j < 4; j++) acc[i][j] = (f32x4){0.f,0.f,0.f,0.f};
  int wrow = (w >> 1) * 64, wcol = (w & 1) * 64;
  for (int k0 = 0; k0 < K; k0 += 64) {
    #pragma unroll
    for (int j = 0; j < 4; j++) {
      int r = w*32 + j*8 + srow;
      int gc = (schunk ^ (r & 7)) * 8;
      const __hip_bfloat16* ga = A + (size_t)(row0 + r)*K + k0 + gc;
      __builtin_amdgcn_global_load_lds((const __attribute__((address_space(1))) void*)ga,
          (__attribute__((address_space(3))) void*)(sA + (w*32 + j*8)*64), 16, 0, 0);
      const __hip_bfloat16* gb = Bw + (size_t)(col0 + r)*K + k0 + gc;
      __builtin_amdgcn_global_load_lds((const __attribute__((address_space(1))) void*)gb,
          (__attribute__((address_space(3))) void*)(sB + (w*32 + j*8)*64), 16, 0, 0);
    }
    __syncthreads();
    #pragma unroll
    for (int ks = 0; ks < 64; ks += 32) {
      short8 af[4], bfv[4];
      #pragma unroll
      for (int mt = 0; mt < 4; mt++) {
        int r = wrow + mt*16 + l16;
        int cch = (ks/8 + quad) ^ (r & 7);
        af[mt] = *(const short8*)(sA + r*64 + cch*8);
      }
      #pragma unroll
      for (int nt = 0; nt < 4; nt++) {
        int r = wcol + nt*16 + l16;
        int cch = (ks/8 + quad) ^ (r & 7);
        bfv[nt] = *(const short8*)(sB + r*64 + cch*8);
      }
      #pragma unroll
      for (int mt = 0; mt < 4; mt++)
        #pragma unroll
        for (int nt = 0; nt < 4; nt++)
          acc[mt][nt] = __builtin_amdgcn_mfma_f32_16x16x32_bf16(af[mt], bfv[nt], acc[mt][nt], 0, 0, 0);
    }
    __syncthreads();
  }
  #pragma unroll
  for (int mt = 0; mt < 4; mt++) {
    int r = row0 + wrow + mt*16 + quad*4;
    #pragma unroll
    for (int nt = 0; nt < 4; nt++) {
      int cidx = col0 + wcol + nt*16 + l16;
      if (cidx < N) {
        float* cp = C + (size_t)r*N + cidx;
        #pragma unroll
        for (int rg = 0; rg < 4; rg++) {
          float v = acc[mt][nt][rg];
          size_t off = (size_t)rg*N;
          if (ADD) cp[off] += v; else cp[off] = v;
        }
      }
    }
  }
}

// ---------------- exact fp32 dt ----------------
__global__ __launch_bounds__(256) void dt_exact(const float* __restrict__ hn, const float* __restrict__ Wi,
                                                const float* __restrict__ dtb, float* __restrict__ dtout) {
  int r = blockIdx.x;
  __shared__ float sh[512];
  __shared__ float red[16][17];
  int t = threadIdx.x;
  sh[t] = hn[(size_t)r*DM + t];
  sh[t+256] = hn[(size_t)r*DM + t + 256];
  __syncthreads();
  int j = t >> 4, seg = t & 15;
  const float* wrow = Wi + (size_t)(2304 + j)*DM + seg*32;
  float p = 0.f;
  #pragma unroll
  for (int k = 0; k < 32; k++) p += sh[seg*32 + k] * wrow[k];
  red[j][seg] = p;
  __syncthreads();
  if (t < 16) {
    float v = 0.f;
    for (int s = 0; s < 16; s++) v += red[t][s];
    v += dtb[t];
    dtout[r*NH + t] = (v > 20.f) ? v : log1pf(__expf(v));
  }
}

// ---------------- depthwise causal conv (width 4) + silu ----------------
__global__ __launch_bounds__(256) void conv_kernel(const float* __restrict__ zx, const float* __restrict__ cw,
                                                   const float* __restrict__ cb, float* __restrict__ xBC) {
  int idx = blockIdx.x*256 + threadIdx.x;
  int r = idx / CONVDIM;
  int c = idx - r*CONVDIM;
  int b = r >> 12, l = r & 4095;
  float acc = cb[c];
  size_t rowb = ((size_t)b << 12) * DINPROJ;
  size_t colbase = 1024 + (size_t)c;
  if (l >= 3) {
    size_t p0 = rowb + (size_t)(l-3)*DINPROJ + colbase;
    acc += zx[p0]*cw[c*4+0] + zx[p0+DINPROJ]*cw[c*4+1]
         + zx[p0+2*DINPROJ]*cw[c*4+2] + zx[p0+3*DINPROJ]*cw[c*4+3];
  } else {
    for (int j = 0; j < 4; j++) {
      int ls = l - 3 + j;
      if (ls >= 0) acc += zx[rowb + (size_t)ls*DINPROJ + colbase]*cw[c*4+j];
    }
  }
  xBC[(size_t)r*CONVDIM + c] = acc / (1.f + __expf(-acc));
}

// ---------------- SSD intra-chunk, MFMA, 1024 threads / 16 waves ----------------
// XCD-swizzled grid: blockIdx = (bc&7) | (h<<3) | ((bc>>3)<<7) so the 16 heads
// sharing one (b,c) B/C tile land on the same XCD L2 (assuming XCD = blkid%8).
__global__ __launch_bounds__(1024) void ssd_intra_mfma(const float* __restrict__ xBC, const float* __restrict__ dt,
                                                       const float* __restrict__ Alog, float* __restrict__ Y,
                                                       float* __restrict__ states, float* __restrict__ acs_buf,
                                                       float* __restrict__ alast) {
  __shared__ short sC[128][136];    // C rows [q][n]; reused for M [q][s]
  __shared__ short sB[128][136];    // B rows [s][n]
  __shared__ short sBwt[128][136];  // (B*w)^T [n][q]
  __shared__ short sXt[64][136];    // X^T [p][q]  (X = xh*dt)
  __shared__ float sa[128], sdt_s[128], sw[128];
  int raw = blockIdx.x;
  int bc = (raw & 7) + ((raw >> 7) << 3);
  int h = (raw >> 3) & 15;
  int b = bc >> 5, c = bc & 31;
  int sblk = bc*16 + h;
  int t = threadIdx.x;
  int w = t >> 6, lane = t & 63, quad = lane >> 4, l16 = lane & 15;
  size_t row0 = (size_t)(b*SEQL + c*CHUNKL);
  float Ah = -__expf(Alog[h]);
  if (t < 128) sdt_s[t] = dt[(row0 + t)*NH + h];
  __syncthreads();
  // wave-0 shuffle scan for cumsum a, weights w, global acs/alast
  if (t < 64) {
    float v0 = sdt_s[2*t] * Ah, v1 = sdt_s[2*t+1] * Ah;
    float s2 = v0 + v1;
    #pragma unroll
    for (int off = 1; off < 64; off <<= 1) {
      float tmp = __shfl_up(s2, off);
      if (t >= off) s2 += tmp;
    }
    float tot = __shfl(s2, 63);
    float pre = s2 - (v0 + v1);
    float a0 = pre + v0, a1 = pre + v0 + v1;
    sa[2*t] = a0; sa[2*t+1] = a1;
    sw[2*t] = __expf(tot - a0); sw[2*t+1] = __expf(tot - a1);
    acs_buf[(size_t)sblk*128 + 2*t]   = a0;
    acs_buf[(size_t)sblk*128 + 2*t+1] = a1;
    if (t == 63) alast[(b*NH + h)*NCHUNK + c] = tot;
  }
  __syncthreads();
  // stage X^T (scaled by dt)
  for (int i = t; i < 128*16; i += 1024) {
    int q = i >> 4, p4 = (i & 15) * 4;
    float4 v = *(const float4*)(xBC + (row0+q)*CONVDIM + h*HD + p4);
    float d = sdt_s[q];
    sXt[p4+0][q] = bfs(v.x*d); sXt[p4+1][q] = bfs(v.y*d);
    sXt[p4+2][q] = bfs(v.z*d); sXt[p4+3][q] = bfs(v.w*d);
  }
  // stage B (rows + weighted transpose) and C (rows)
  for (int i = t; i < 128*64; i += 1024) {
    int q = i >> 6, n4 = (i & 63) * 4;
    float4 v = *(const float4*)(xBC + (row0+q)*CONVDIM + DIN + n4);
    if (n4 < DSTATE) {
      short4v pk = { bfs(v.x), bfs(v.y), bfs(v.z), bfs(v.w) };
      *(short4v*)&sB[q][n4] = pk;
      float wq = sw[q];
      sBwt[n4+0][q] = bfs(v.x*wq); sBwt[n4+1][q] = bfs(v.y*wq);
      sBwt[n4+2][q] = bfs(v.z*wq); sBwt[n4+3][q] = bfs(v.w*wq);
    } else {
      int n = n4 - DSTATE;
      short4v pk = { bfs(v.x), bfs(v.y), bfs(v.z), bfs(v.w) };
      *(short4v*)&sC[q][n] = pk;
    }
  }
  __syncthreads();
  // step1: G = C·B^T   (wave w: m-tile w>>1, n-tiles (w&1)*4..+3)
  int mt1 = w >> 1, nt1 = (w & 1) * 4;
  f32x4 g[4];
  #pragma unroll
  for (int j = 0; j < 4; j++) g[j] = (f32x4){0.f,0.f,0.f,0.f};
  #pragma unroll
  for (int ks = 0; ks < 128; ks += 32) {
    short8 af = *(const short8*)&sC[mt1*16 + l16][ks + quad*8];
    #pragma unroll
    for (int j = 0; j < 4; j++) {
      short8 bfv = *(const short8*)&sB[(nt1+j)*16 + l16][ks + quad*8];
      g[j] = __builtin_amdgcn_mfma_f32_16x16x32_bf16(af, bfv, g[j], 0, 0, 0);
    }
  }
  // step4: states = X^T·(Bw)  (wave w: p-tile w>>2, n-tiles (w&3)*2..+1)
  int pt4 = w >> 2, nt4 = (w & 3) * 2;
  f32x4 st[2];
  st[0] = (f32x4){0.f,0.f,0.f,0.f}; st[1] = (f32x4){0.f,0.f,0.f,0.f};
  #pragma unroll
  for (int ks = 0; ks < 128; ks += 32) {
    short8 af = *(const short8*)&sXt[pt4*16 + l16][ks + quad*8];
    #pragma unroll
    for (int j = 0; j < 2; j++) {
      short8 bfv = *(const short8*)&sBwt[(nt4+j)*16 + l16][ks + quad*8];
      st[j] = __builtin_amdgcn_mfma_f32_16x16x32_bf16(af, bfv, st[j], 0, 0, 0);
    }
  }
  __syncthreads();   // step1's sC reads done everywhere
  // write M = L ⊙ G into sC
  #pragma unroll
  for (int j = 0; j < 4; j++) {
    int s = (nt1+j)*16 + l16;
    #pragma unroll
    for (int rg = 0; rg < 4; rg++) {
      int q = mt1*16 + quad*4 + rg;
      float m = (s <= q) ? g[j][rg] * __expf(sa[q] - sa[s]) : 0.f;
      sC[q][s] = bfs(m);
    }
  }
  __syncthreads();
  // step3: Y_diag = M·X  (wave w: m-tile w>>1, p-tiles (w&1)*2..+1)
  int mt3 = w >> 1, pt3 = (w & 1) * 2;
  f32x4 y4[2];
  y4[0] = (f32x4){0.f,0.f,0.f,0.f}; y4[1] = (f32x4){0.f,0.f,0.f,0.f};
  #pragma unroll
  for (int ks = 0; ks < 128; ks += 32) {
    short8 af = *(const short8*)&sC[mt3*16 + l16][ks + quad*8];
    #pragma unroll
    for (int j = 0; j < 2; j++) {
      short8 bfv = *(const short8*)&sXt[(pt3+j)*16 + l16][ks + quad*8];
      y4[j] = __builtin_amdgcn_mfma_f32_16x16x32_bf16(af, bfv, y4[j], 0, 0, 0);
    }
  }
  // epilogue
  #pragma unroll
  for (int j = 0; j < 2; j++) {
    int p = (pt3+j)*16 + l16;
    #pragma unroll
    for (int rg = 0; rg < 4; rg++) {
      int q = mt3*16 + quad*4 + rg;
      Y[(row0 + q)*DIN + h*HD + p] = y4[j][rg];
    }
  }
  float* sp = states + (size_t)sblk*(HD*DSTATE);
  #pragma unroll
  for (int j = 0; j < 2; j++) {
    int n = (nt4+j)*16 + l16;
    #pragma unroll
    for (int rg = 0; rg < 4; rg++) {
      int p = pt4*16 + quad*4 + rg;
      sp[(size_t)p*DSTATE + n] = st[j][rg];
    }
  }
}

// ---------------- inter-chunk scan ----------------
__global__ __launch_bounds__(256) void ssd_scan2(float* __restrict__ states, const float* __restrict__ alast) {
  int idx = blockIdx.x*256 + threadIdx.x;     // 2*16*8192
  int b = idx >> 17;
  int h = (idx >> 13) & 15;
  int pn = idx & 8191;
  const float* al = alast + (b*NH + h)*NCHUNK;
  float S = 0.f;
  for (int c = 0; c < NCHUNK; c++) {
    size_t base = ((size_t)((b*NCHUNK + c)*NH + h))*8192 + pn;
    float dec = __expf(al[c]);
    float tmp = states[base];
    states[base] = S;
    S = dec*S + tmp;
  }
}

// ---------------- SSD off-diagonal, MFMA ----------------
__global__ __launch_bounds__(256) void ssd_off_mfma(const float* __restrict__ xBC, const float* __restrict__ states,
                                                    const float* __restrict__ acs_buf, const float* __restrict__ Dvec,
                                                    float* __restrict__ Y) {
  __shared__ short sC[128][136];   // C rows [q][n]
  __shared__ short sS[64][136];    // S rows [p][n]
  __shared__ float sa[128];
  int raw = blockIdx.x;
  int bc = (raw & 7) + ((raw >> 7) << 3);
  int h = (raw >> 3) & 15;
  int b = bc >> 5, c = bc & 31;
  int sblk = bc*16 + h;
  int t = threadIdx.x;
  int w = t >> 6, lane = t & 63, quad = lane >> 4, l16 = lane & 15;
  size_t row0 = (size_t)(b*SEQL + c*CHUNKL);
  const float* sbase = states + (size_t)sblk*(HD*DSTATE);
  for (int i = t; i < 128*32; i += 256) {
    int q = i >> 5, n4 = (i & 31) * 4;
    float4 v = *(const float4*)(xBC + (row0+q)*CONVDIM + DIN + DSTATE + n4);
    short4v pk = { bfs(v.x), bfs(v.y), bfs(v.z), bfs(v.w) };
    *(short4v*)&sC[q][n4] = pk;
  }
  for (int i = t; i < 64*32; i += 256) {
    int p = i >> 5, n4 = (i & 31) * 4;
    float4 v = *(const float4*)(sbase + (size_t)p*DSTATE + n4);
    short4v pk = { bfs(v.x), bfs(v.y), bfs(v.z), bfs(v.w) };
    *(short4v*)&sS[p][n4] = pk;
  }
  if (t < 128) sa[t] = acs_buf[(size_t)sblk*128 + t];
  __syncthreads();
  f32x4 acc[2][4];
  #pragma unroll
  for (int mt = 0; mt < 2; mt++)
    #pragma unroll
    for (int nt = 0; nt < 4; nt++) acc[mt][nt] = (f32x4){0.f,0.f,0.f,0.f};
  #pragma unroll
  for (int ks = 0; ks < 128; ks += 32) {
    short8 af[2], bfv[4];
    #pragma unroll
    for (int mt = 0; mt < 2; mt++) af[mt] = *(const short8*)&sC[(w*2+mt)*16 + l16][ks + quad*8];
    #pragma unroll
    for (int nt = 0; nt < 4; nt++) bfv[nt] = *(const short8*)&sS[nt*16 + l16][ks + quad*8];
    #pragma unroll
    for (int mt = 0; mt < 2; mt++)
      #pragma unroll
      for (int nt = 0; nt < 4; nt++)
        acc[mt][nt] = __builtin_amdgcn_mfma_f32_16x16x32_bf16(af[mt], bfv[nt], acc[mt][nt], 0, 0, 0);
  }
  float Dh = Dvec[h];
  #pragma unroll
  for (int mt = 0; mt < 2; mt++) {
    int qb = (w*2+mt)*16 + quad*4;
    #pragma unroll
    for (int rg = 0; rg < 4; rg++) {
      int q = qb + rg;
      float ea = __expf(sa[q]);
      #pragma unroll
      for (int nt = 0; nt < 4; nt++) {
        int p = nt*16 + l16;
        size_t yi = (row0 + q)*DIN + h*HD + p;
        Y[yi] += ea*acc[mt][nt][rg] + Dh*xBC[(row0+q)*CONVDIM + h*HD + p];
      }
    }
  }
}

// ---------------- gate (silu(z)) + RMSNorm -> bf16 ----------------
__global__ __launch_bounds__(256) void gate_rms(const float* __restrict__ zx, const float* __restrict__ Y,
                                                const float* __restrict__ rw, __hip_bfloat16* __restrict__ out) {
  int r = blockIdx.x;
  int t = threadIdx.x;
  float yz[4];
  float ss = 0.f;
  for (int i = 0; i < 4; i++) {
    int idx = t + i*256;
    float z = zx[(size_t)r*DINPROJ + idx];
    float y = Y[(size_t)r*DIN + idx];
    float v = y * z / (1.f + __expf(-z));
    yz[i] = v; ss += v*v;
  }
  for (int o = 32; o > 0; o >>= 1) ss += __shfl_down(ss, o);
  __shared__ float red[4];
  int lane = t & 63, wv = t >> 6;
  if (lane == 0) red[wv] = ss;
  __syncthreads();
  ss = red[0]+red[1]+red[2]+red[3];
  float rs = rsqrtf(ss*(1.f/DIN) + 1e-5f);
  for (int i = 0; i < 4; i++) {
    int idx = t + i*256;
    out[(size_t)r*DIN + idx] = __float2bfloat16(yz[i]*rs*rw[idx]);
  }
}

extern "C" void kernel_launch(void* const* d_in, const int* in_sizes, int n_in,
                              void* d_out, int out_size, void* d_ws, size_t ws_size,
                              hipStream_t stream) {
  (void)in_sizes; (void)n_in; (void)out_size; (void)ws_size;
  const float* x    = (const float*)d_in[0];
  const float* Wi   = (const float*)d_in[1];
  const float* cw   = (const float*)d_in[2];
  const float* cb   = (const float*)d_in[3];
  const float* dtb  = (const float*)d_in[4];
  const float* Alog = (const float*)d_in[5];
  const float* Dv   = (const float*)d_in[6];
  const float* rw   = (const float*)d_in[7];
  const float* Wo   = (const float*)d_in[8];
  const float* lnw  = (const float*)d_in[9];
  const float* lnb  = (const float*)d_in[10];
  const float* flnw = (const float*)d_in[11];
  const float* flnb = (const float*)d_in[12];
  float* out = (float*)d_out;

  float* p = (float*)d_ws;
  float* buf_h   = p; p += (size_t)ROWS*DM;
  float* buf_hn  = p; p += (size_t)ROWS*DM;
  float* buf_zx  = p; p += (size_t)ROWS*DINPROJ;
  float* buf_xBC = p; p += (size_t)ROWS*CONVDIM;
  float* buf_dt  = p; p += (size_t)ROWS*NH;
  float* buf_Y   = p; p += (size_t)ROWS*DIN;
  float* buf_st  = p; p += (size_t)BQ*NCHUNK*NH*HD*DSTATE;
  float* buf_acs = p; p += (size_t)BQ*NCHUNK*NH*CHUNKL;
  float* buf_al  = p; p += (size_t)BQ*NH*NCHUNK;
  __hip_bfloat16* bp = (__hip_bfloat16*)p;
  __hip_bfloat16* wi_b = bp; bp += (size_t)6*NPAD*DM;
  __hip_bfloat16* wo_b = bp; bp += (size_t)6*DM*DIN;
  __hip_bfloat16* hn_b = bp; bp += (size_t)ROWS*DM;
  __hip_bfloat16* y_b  = bp; bp += (size_t)ROWS*DIN;

  hipMemcpyAsync(buf_h, x, (size_t)ROWS*DM*sizeof(float), hipMemcpyDeviceToDevice, stream);
  cvt_wi<<<6*NPAD*DM/256, 256, 0, stream>>>(Wi, wi_b);
  cvt_wo<<<6*DM*DIN/256, 256, 0, stream>>>(Wo, wo_b);

  for (int i = 0; i < 6; i++) {
    ln_kernel<<<ROWS, 256, 0, stream>>>(buf_h, lnw + i*DM, lnb + i*DM, buf_hn, hn_b);
    dt_exact<<<ROWS, 256, 0, stream>>>(buf_hn, Wi + (size_t)i*DINPROJ*DM, dtb + i*NH, buf_dt);
    gemm_bf16<false><<<dim3(NPAD/128, ROWS/128), 256, 0, stream>>>(
        hn_b, wi_b + (size_t)i*NPAD*DM, buf_zx, DINPROJ, DM);
    conv_kernel<<<ROWS*CONVDIM/256, 256, 0, stream>>>(
        buf_zx, cw + (size_t)i*CONVDIM*DCONV, cb + i*CONVDIM, buf_xBC);
    ssd_intra_mfma<<<BQ*NCHUNK*NH, 1024, 0, stream>>>(
        buf_xBC, buf_dt, Alog + i*NH, buf_Y, buf_st, buf_acs, buf_al);
    ssd_scan2<<<BQ*NH*HD*DSTATE/256, 256, 0, stream>>>(buf_st, buf_al);
    ssd_off_mfma<<<BQ*NCHUNK*NH, 256, 0, stream>>>(buf_xBC, buf_st, buf_acs, Dv + i*NH, buf_Y);
    gate_rms<<<ROWS, 256, 0, stream>>>(buf_zx, buf_Y, rw + i*DIN, y_b);
    gemm_bf16<true><<<dim3(DM/128, ROWS/128), 256, 0, stream>>>(
        y_b, wo_b + (size_t)i*DM*DIN, buf_h, DM, DIN);
  }
  ln_kernel<<<ROWS, 256, 0, stream>>>(buf_h, flnw, flnb, out, nullptr);
}